// Round 14
// baseline (98.763 us; speedup 1.0000x reference)
//
#include <hip/hip_runtime.h>
#include <cstdint>
#include <cmath>

#define DEV __device__ __forceinline__

constexpr int SEL = 20;
constexpr int NSTEP2 = 10, NSTEP3 = 22, NSTEPS = 32;
constexpr int L2 = SEL + 1;   // 21 bits, group2
constexpr int L3 = SEL;       // 20 bits, group3
constexpr int P = 2;          // Chebyshev nodes (linear barycentric; verified r11/r12)
constexpr int FBE = 7;        // enumerated low bits
constexpr int FBS2 = L2 - FBE;   // 14
constexpr int FBS3 = L3 - FBE;   // 13
constexpr int NPAT2 = 1 << FBS2; // 16384
constexpr int NPAT3 = 1 << FBS3; // 8192
constexpr int BT = 128;          // block threads for ka/kc

typedef float v2f __attribute__((ext_vector_type(2)));

// ---- ws layout (float indices) ----
constexpr int OFF_T      = 0;                               // T[2][22][P] = 88
constexpr int OFF_SUMS   = OFF_T + 2 * 22 * P;
constexpr int SUMS_STRIDE = 96;
constexpr int OFF_PCHAIN = OFF_SUMS + NSTEPS * SUMS_STRIDE;
constexpr int OFF_KEYB   = OFF_PCHAIN + 40;
constexpr int OFF_CT     = OFF_KEYB + 128;
constexpr int OFF_CB     = OFF_CT + 32;
constexpr int OFF_NEED   = OFF_CB + 32;
constexpr int OFF_ZEND   = OFF_NEED + 8;                    // zero range end
constexpr int OFF_PAT2   = OFF_ZEND;                        // uint[16384]
constexpr int OFF_PAT3   = OFF_PAT2 + NPAT2;                // uint[8192]

constexpr float K2E = 2.8853900817779268f;   // 2*log2(e)
constexpr float KE  = 1.4426950408889634f;   // log2(e)

constexpr float CP0 = 0.85355339059f, CP1 = 0.14644660941f; // 2-node Chebyshev on (0,1)

struct Binom { unsigned v[22][22]; };
constexpr Binom make_binom() {
  Binom b{};
  for (int n = 0; n < 22; n++) {
    b.v[n][0] = 1;
    for (int k = 1; k < 22; k++)
      b.v[n][k] = (k > n) ? 0u : (k == n ? 1u : b.v[n - 1][k - 1] + b.v[n - 1][k]);
  }
  return b;
}
__device__ constexpr Binom BN = make_binom();

DEV float fast_tanh(float x) {
  float e = exp2f(x * K2E);
  return 1.0f - 2.0f * __builtin_amdgcn_rcpf(e + 1.0f);
}
DEV float fast_exp(float x) { return exp2f(x * KE); }
DEV void gatomic(float* p, float v) { unsafeAtomicAdd(p, v); }

DEV unsigned gosper(unsigned cmb) {
  unsigned u = cmb & (~cmb + 1u);
  unsigned v = cmb + u;
  return v | ((cmb ^ v) >> (1 + __ffs(u)));
}

// wave64 sum via DPP (verified r12). Total lands in lane 63.
DEV float dppsum64(float x) {
  float f = x;
  f += __int_as_float(__builtin_amdgcn_update_dpp(0, __float_as_int(f), 0x111, 0xf, 0xf, false));
  f += __int_as_float(__builtin_amdgcn_update_dpp(0, __float_as_int(f), 0x112, 0xf, 0xf, false));
  f += __int_as_float(__builtin_amdgcn_update_dpp(0, __float_as_int(f), 0x114, 0xf, 0xf, false));
  f += __int_as_float(__builtin_amdgcn_update_dpp(0, __float_as_int(f), 0x118, 0xf, 0xf, false));
  f += __int_as_float(__builtin_amdgcn_update_dpp(0, __float_as_int(f), 0x142, 0xa, 0xf, false));
  f += __int_as_float(__builtin_amdgcn_update_dpp(0, __float_as_int(f), 0x143, 0xc, 0xf, false));
  return f;   // valid in lane 63 of the wave
}

// quad_perm DPP helper — ctrl must be an immediate, so template parameter
template<int CTRL>
DEV float qperm(float x) {
  return __int_as_float(__builtin_amdgcn_update_dpp(0, __float_as_int(x), CTRL, 0xf, 0xf, false));
}

// =================== Kernel Z: init + popc-sorted pattern tables ===================
__global__ void kz(const float* p0, const float* sel,
                   const float* W1_2, const float* b1_2,
                   const float* W1_3, const float* b1_3, float* ws) {
  int tx = threadIdx.x;
  if (blockIdx.x == 0) {
    for (int i = tx; i < OFF_ZEND; i += blockDim.x) ws[i] = 0.0f;
    __syncthreads();
    if (tx < NSTEPS) {
      int t = tx;
      int g = (t < NSTEP2) ? 0 : 1;
      int L = g ? L3 : L2;
      const float* sbase = sel + (g ? (NSTEP2 * L2 + (t - NSTEP2) * L3) : t * L2);
      unsigned cb = 0; int c = 0;
      for (int d = 0; d < L; d++)
        if (sbase[d] > 0.5f) { cb |= 1u << d; c++; }
      ((int*)ws)[OFF_CT + t] = c;
      ((unsigned*)ws)[OFF_CB + t] = cb;
      atomicOr(&((unsigned*)ws)[OFF_NEED + g], 1u << c);
      const float* W1 = g ? W1_3 : W1_2;
      const float* b1 = g ? b1_3 : b1_2;
      for (int h = 0; h < 4; h++) {
        float s = b1[h];
        for (int d = 0; d < L; d++)
          if ((cb >> d) & 1) s += W1[h * (L + 1) + 1 + d];
        ws[OFF_KEYB + t * 4 + h] = s;
      }
      if (tx == 0) ws[OFF_PCHAIN] = p0[0];
    }
  } else {
    int r = (blockIdx.x - 1) * 256 + tx;   // 0..24575
    int NB, rr, off;
    if (r < NPAT2) { NB = FBS2; rr = r; off = OFF_PAT2; }
    else           { NB = FBS3; rr = r - NPAT2; off = OFF_PAT3; }
    int k = 0; unsigned base = 0;
    for (int kk = 0; kk <= NB; kk++) {
      unsigned sz = BN.v[NB][kk];
      if ((unsigned)rr < base + sz) { k = kk; break; }
      base += sz;
    }
    unsigned local = (unsigned)rr - base;
    unsigned pat = 0; int kk = k;
    for (int bb = NB - 1; bb >= 0 && kk > 0; bb--) {
      unsigned cnt = BN.v[bb][kk];
      if (local >= cnt) { pat |= 1u << bb; local -= cnt; kk--; }
    }
    ((unsigned*)ws)[off + rr] = pat;
  }
}

// =================== shared tab builder (BT threads) ===================
template<int LL>
DEV void build_tabs(const float* W1, float4 add,
                    float4* tabEX, float4* tabS0, float4* tabS1) {
  constexpr int NS1 = 1 << (LL - 14);
  int tx = threadIdx.x;
  for (int i = tx; i < 256 + NS1; i += BT) {
    if (i < 128) {
      int e = i;
      float s0 = 0, s1 = 0, s2 = 0, s3 = 0;
      for (int j = 0; j < 7; j++) if ((e >> j) & 1) {
        s0 += W1[0 * (LL + 1) + 1 + j]; s1 += W1[1 * (LL + 1) + 1 + j];
        s2 += W1[2 * (LL + 1) + 1 + j]; s3 += W1[3 * (LL + 1) + 1 + j];
      }
      tabEX[e] = make_float4(exp2f(K2E * s0), exp2f(K2E * s1), exp2f(K2E * s2), exp2f(K2E * s3));
    } else if (i < 256) {
      int e = i - 128;
      float s0 = add.x, s1 = add.y, s2 = add.z, s3 = add.w;
      for (int j = 0; j < 7; j++) if ((e >> j) & 1) {
        s0 += W1[0 * (LL + 1) + 1 + 7 + j]; s1 += W1[1 * (LL + 1) + 1 + 7 + j];
        s2 += W1[2 * (LL + 1) + 1 + 7 + j]; s3 += W1[3 * (LL + 1) + 1 + 7 + j];
      }
      tabS0[e] = make_float4(s0, s1, s2, s3);
    } else {
      int e = i - 256;
      float s0 = 0, s1 = 0, s2 = 0, s3 = 0;
      for (int j = 0; j < LL - 14; j++) if ((e >> j) & 1) {
        s0 += W1[0 * (LL + 1) + 1 + 14 + j]; s1 += W1[1 * (LL + 1) + 1 + 14 + j];
        s2 += W1[2 * (LL + 1) + 1 + 14 + j]; s3 += W1[3 * (LL + 1) + 1 + 14 + j];
      }
      tabS1[e] = make_float4(s0, s1, s2, s3);
    }
  }
}

// =================== Kernel A: per-class tabulation of T[g][c][j] ===================
constexpr int KA_B2 = NPAT2 / BT;  // 128
constexpr int KA_B3 = NPAT3 / BT;  // 64
constexpr int KA_BLOCKS = 22 * KA_B2 + 21 * KA_B3;

template<int LL>
DEV void ka_work(int g, int c, int sub,
                 const float* W1, const float* b1, const float* W2, const float* b2,
                 float* ws, float4* tabEX, float4* tabS0, float4* tabS1, float* sT) {
  int tx = threadIdx.x;
  const unsigned* pats = ((const unsigned*)ws) + (LL == 21 ? OFF_PAT2 : OFF_PAT3);
  // popc-range early exit (patterns sorted by popc ascending)
  int pcFirst = __popc(pats[sub * BT]);
  int pcLast  = __popc(pats[sub * BT + BT - 1]);
  if (c < pcFirst || c - pcLast > FBE) return;
  float4 add = make_float4(b1[0], b1[1], b1[2], b1[3]);
  build_tabs<LL>(W1, add, tabEX, tabS0, tabS1);
  if (tx < P) sT[tx] = 0.0f;
  __syncthreads();
  unsigned pat = pats[sub * BT + tx];
  int ce = c - __popc(pat);
  int trip = (ce >= 0 && ce <= FBE) ? (int)BN.v[FBE][ce] : 0;
  if (__any(trip > 0)) {
    float4 vS0 = tabS0[pat & 127];
    float4 vS1 = tabS1[pat >> 7];
    float E0 = exp2f(K2E * (vS0.x + vS1.x));
    float E1 = exp2f(K2E * (vS0.y + vS1.y));
    float E2 = exp2f(K2E * (vS0.z + vS1.z));
    float E3 = exp2f(K2E * (vS0.w + vS1.w));
    float a0 = W1[0], a1 = W1[LL + 1], a2 = W1[2 * (LL + 1)], a3 = W1[3 * (LL + 1)];
    float w0 = W2[0], w1 = W2[1], w2 = W2[2], w3 = W2[3];
    float W0 = b2[0] + w0 + w1 + w2 + w3;
    float m0 = -2.0f * w0, m1 = -2.0f * w1, m2 = -2.0f * w2, m3 = -2.0f * w3;
    float EA00 = E0 * exp2f(K2E * CP0 * a0), EA01 = E1 * exp2f(K2E * CP0 * a1);
    float EA02 = E2 * exp2f(K2E * CP0 * a2), EA03 = E3 * exp2f(K2E * CP0 * a3);
    float EA10 = E0 * exp2f(K2E * CP1 * a0), EA11 = E1 * exp2f(K2E * CP1 * a1);
    float EA12 = E2 * exp2f(K2E * CP1 * a2), EA13 = E3 * exp2f(K2E * CP1 * a3);
    float acc0 = 0.0f, acc1 = 0.0f;
    unsigned iv = (trip > 0) ? ((1u << ce) - 1u) : 0u;
    float4 tE = tabEX[iv & 127];
#pragma unroll 1
    for (int k = 0; k < trip; k++) {
      float4 cur = tE;
      iv = gosper(iv);
      tE = tabEX[iv & 127];   // prefetch next (garbage on last iter, unused)
      float o0 = W0, o1 = W0, rr;
      rr = __builtin_amdgcn_rcpf(fmaf(cur.x, EA00, 1.0f)); o0 = fmaf(m0, rr, o0);
      rr = __builtin_amdgcn_rcpf(fmaf(cur.y, EA01, 1.0f)); o0 = fmaf(m1, rr, o0);
      rr = __builtin_amdgcn_rcpf(fmaf(cur.z, EA02, 1.0f)); o0 = fmaf(m2, rr, o0);
      rr = __builtin_amdgcn_rcpf(fmaf(cur.w, EA03, 1.0f)); o0 = fmaf(m3, rr, o0);
      rr = __builtin_amdgcn_rcpf(fmaf(cur.x, EA10, 1.0f)); o1 = fmaf(m0, rr, o1);
      rr = __builtin_amdgcn_rcpf(fmaf(cur.y, EA11, 1.0f)); o1 = fmaf(m1, rr, o1);
      rr = __builtin_amdgcn_rcpf(fmaf(cur.z, EA12, 1.0f)); o1 = fmaf(m2, rr, o1);
      rr = __builtin_amdgcn_rcpf(fmaf(cur.w, EA13, 1.0f)); o1 = fmaf(m3, rr, o1);
      acc0 += exp2f(KE * o0);
      acc1 += exp2f(KE * o1);
    }
    float v0 = dppsum64(acc0), v1 = dppsum64(acc1);
    if ((tx & 63) == 63) {
      if (v0 != 0.0f) atomicAdd(&sT[0], v0);
      if (v1 != 0.0f) atomicAdd(&sT[1], v1);
    }
  }
  __syncthreads();
  if (tx < P) {
    float v = sT[tx];
    if (v != 0.0f) gatomic(&ws[OFF_T + (g * 22 + c) * P + tx], v);
  }
}

__global__ __launch_bounds__(BT) void ka(
    const float* W1_2, const float* b1_2, const float* W2_2, const float* b2_2,
    const float* W1_3, const float* b1_3, const float* W2_3, const float* b2_3,
    float* ws) {
  __shared__ float4 tabEX[128], tabS0[128], tabS1[128];
  __shared__ float sT[P];
  int b = blockIdx.x;
  int g, c, sub;
  if (b < 22 * KA_B2) { g = 0; c = b / KA_B2; sub = b % KA_B2; }
  else { int b3 = b - 22 * KA_B2; g = 1; c = b3 / KA_B3; sub = b3 % KA_B3; }
  unsigned need = ((const unsigned*)ws)[OFF_NEED + g];
  if (!((need >> c) & 1)) return;
  if (g == 0) ka_work<21>(0, c, sub, W1_2, b1_2, W2_2, b2_2, ws, tabEX, tabS0, tabS1, sT);
  else        ka_work<20>(1, c, sub, W1_3, b1_3, W2_3, b2_3, ws, tabEX, tabS0, tabS1, sT);
}

// =================== Kernel B: prob chain, 64-lane cooperative ===================
__global__ __launch_bounds__(64) void kb(const float* p0in,
                   const float* W1_2, const float* b1_2, const float* W2_2, const float* b2_2,
                   const float* W1_3, const float* b1_3, const float* W2_3, const float* b2_3,
                   float* ws, float* out) {
  __shared__ float sT[2 * 22 * P];
  __shared__ float sKEYB[128], sW1c0[8], sW2[8], sB2[2];
  __shared__ int sCT[32];
  int lane = threadIdx.x;
  for (int i = lane; i < 2 * 22 * P; i += 64) sT[i] = ws[OFF_T + i];
  for (int i = lane; i < 128; i += 64) sKEYB[i] = ws[OFF_KEYB + i];
  if (lane < 32) sCT[lane] = ((const int*)ws)[OFF_CT + lane];
  if (lane < 4) {
    sW1c0[lane]     = W1_2[lane * (L2 + 1)];
    sW1c0[4 + lane] = W1_3[lane * (L3 + 1)];
    sW2[lane]     = W2_2[lane];
    sW2[4 + lane] = W2_3[lane];
  }
  if (lane == 0) { sB2[0] = b2_2[0]; sB2[1] = b2_3[0]; }
  __syncthreads();
  float p = p0in[0];
  if (lane == 0) out[0] = p;
  int h = lane & 3;
#pragma unroll 1
  for (int tt = 0; tt < NSTEPS; tt++) {
    int g = (tt < NSTEP2) ? 0 : 1;
    int c = sCT[tt];
    float hk = fast_tanh(sKEYB[tt * 4 + h] + p * sW1c0[g * 4 + h]);
    float contrib = sW2[g * 4 + h] * hk;
    contrib += qperm<0xB1>(contrib);   // xor 1 within quad
    contrib += qperm<0x4E>(contrib);   // xor 2 within quad
    float outk = sB2[g] + contrib;
    float T0 = sT[(g * 22 + c) * P + 0], T1 = sT[(g * 22 + c) * P + 1];
    float d0 = p - CP0; if (fabsf(d0) < 1e-9f) d0 = (d0 < 0.0f) ? -1e-9f : 1e-9f;
    float d1 = p - CP1; if (fabsf(d1) < 1e-9f) d1 = (d1 < 0.0f) ? -1e-9f : 1e-9f;
    float q0 = 1.0f / d0, q1 = -1.0f / d1;
    float Se = (q0 * T0 + q1 * T1) / (q0 + q1);
    p = fast_exp(outk) / Se;
    if (lane == 0) { out[1 + tt] = p; ws[OFF_PCHAIN + 1 + tt] = p; }
  }
}

// =================== Kernel C: popc-sorted structural enumeration ===================
constexpr int KC_B2 = NPAT2 / BT;   // 128 blocks/step (g2)
constexpr int KC_B3 = NPAT3 / BT;   // 64 blocks/step (g3)
constexpr int KC_BLOCKS = NSTEP2 * KC_B2 + NSTEP3 * KC_B3;  // 2688

template<int LL>
DEV void kc_work(int t, int sub,
                 const float* W1, const float* b1, const float* W2, const float* b2,
                 float* ws, float4* tabEX, float4* tabS0, float4* tabS1, float* sS) {
  constexpr int FS = LL - FBE;   // structural bit count: 14 / 13
  int tx = threadIdx.x;
  int c = ((const int*)ws)[OFF_CT + t];
  const unsigned* pats = ((const unsigned*)ws) + (LL == 21 ? OFF_PAT2 : OFF_PAT3);
  int pcFirst = __popc(pats[sub * BT]);
  int pcLast  = __popc(pats[sub * BT + BT - 1]);
  if (c < pcFirst || c - pcLast > FBE) return;
  float p = ws[OFF_PCHAIN + t];
  float4 add = make_float4(b1[0] + p * W1[0 * (LL + 1)], b1[1] + p * W1[1 * (LL + 1)],
                           b1[2] + p * W1[2 * (LL + 1)], b1[3] + p * W1[3 * (LL + 1)]);
  build_tabs<LL>(W1, add, tabEX, tabS0, tabS1);
  if (tx < SUMS_STRIDE) sS[tx] = 0.0f;
  __syncthreads();
  unsigned pat = pats[sub * BT + tx];
  int ce = c - __popc(pat);
  int trip = (ce >= 0 && ce <= FBE) ? (int)BN.v[FBE][ce] : 0;
  if (__any(trip > 0)) {
    float4 vS0 = tabS0[pat & 127];
    float4 vS1 = tabS1[pat >> 7];
    float EbS0 = exp2f(K2E * (vS0.x + vS1.x));
    float EbS1 = exp2f(K2E * (vS0.y + vS1.y));
    float EbS2 = exp2f(K2E * (vS0.z + vS1.z));
    float EbS3 = exp2f(K2E * (vS0.w + vS1.w));
    float w0 = W2[0], w1 = W2[1], w2 = W2[2], w3 = W2[3];
    float b2s = b2[0];

    float aE = 0.0f, aW = 0.0f;
    v2f aQa = {0, 0}, aQb = {0, 0}, aWHa = {0, 0}, aWHb = {0, 0};
#define G_DECL(k) v2f g##k##a = {0, 0}, g##k##b = {0, 0};
    G_DECL(0) G_DECL(1) G_DECL(2) G_DECL(3) G_DECL(4) G_DECL(5) G_DECL(6)
#undef G_DECL

    unsigned iv = (trip > 0) ? ((1u << ce) - 1u) : 0u;
    float4 tE = tabEX[iv & 127];
#pragma unroll 1
    for (int k = 0; k < trip; k++) {
      float4 cur = tE;
      unsigned ivc = iv;
      iv = gosper(iv);
      tE = tabEX[iv & 127];   // prefetch next (garbage on last iter, unused)
      float r0 = __builtin_amdgcn_rcpf(fmaf(cur.x, EbS0, 1.0f));
      float r1 = __builtin_amdgcn_rcpf(fmaf(cur.y, EbS1, 1.0f));
      float r2 = __builtin_amdgcn_rcpf(fmaf(cur.z, EbS2, 1.0f));
      float r3 = __builtin_amdgcn_rcpf(fmaf(cur.w, EbS3, 1.0f));
      float t0 = fmaf(-2.0f, r0, 1.0f);
      float t1 = fmaf(-2.0f, r1, 1.0f);
      float t2 = fmaf(-2.0f, r2, 1.0f);
      float t3 = fmaf(-2.0f, r3, 1.0f);
      float outv = b2s + w0 * t0 + w1 * t1 + w2 * t2 + w3 * t3;
      float e = fast_exp(outv);
      float q0 = outv * (1.0f - t0 * t0) * w0;
      float q1 = outv * (1.0f - t1 * t1) * w1;
      float q2 = outv * (1.0f - t2 * t2) * w2;
      float q3 = outv * (1.0f - t3 * t3) * w3;
      v2f qa = {q0, q1}, qb = {q2, q3};
      aE += e; aW += outv;
      aQa += qa; aQb += qb;
      v2f ov = {outv, outv};
      v2f ta = {t0, t1}, tb = {t2, t3};
      aWHa += ov * ta; aWHb += ov * tb;
#define G_UPD(k) { float bd = (float)((ivc >> k) & 1u); v2f bdv = {bd, bd}; \
      g##k##a += bdv * qa; g##k##b += bdv * qb; }
      G_UPD(0) G_UPD(1) G_UPD(2) G_UPD(3) G_UPD(4) G_UPD(5) G_UPD(6)
#undef G_UPD
    }

    // ---- epilogue (DPP reductions, lane 63 holds totals) ----
    int lane = tx & 63;
    float rr;
    rr = dppsum64(aE); if (lane == 63 && rr != 0.0f) atomicAdd(&sS[0], rr);
    rr = dppsum64(aW); if (lane == 63 && rr != 0.0f) atomicAdd(&sS[1], rr);
    rr = dppsum64(aQa.x); if (lane == 63 && rr != 0.0f) atomicAdd(&sS[2], rr);
    rr = dppsum64(aQa.y); if (lane == 63 && rr != 0.0f) atomicAdd(&sS[3], rr);
    rr = dppsum64(aQb.x); if (lane == 63 && rr != 0.0f) atomicAdd(&sS[4], rr);
    rr = dppsum64(aQb.y); if (lane == 63 && rr != 0.0f) atomicAdd(&sS[5], rr);
    rr = dppsum64(aWHa.x); if (lane == 63 && rr != 0.0f) atomicAdd(&sS[6], rr);
    rr = dppsum64(aWHa.y); if (lane == 63 && rr != 0.0f) atomicAdd(&sS[7], rr);
    rr = dppsum64(aWHb.x); if (lane == 63 && rr != 0.0f) atomicAdd(&sS[8], rr);
    rr = dppsum64(aWHb.y); if (lane == 63 && rr != 0.0f) atomicAdd(&sS[9], rr);
#define GF(k) { \
    rr = dppsum64(g##k##a.x); if (lane == 63 && rr != 0.0f) atomicAdd(&sS[10 + 0 * 21 + k], rr); \
    rr = dppsum64(g##k##a.y); if (lane == 63 && rr != 0.0f) atomicAdd(&sS[10 + 1 * 21 + k], rr); \
    rr = dppsum64(g##k##b.x); if (lane == 63 && rr != 0.0f) atomicAdd(&sS[10 + 2 * 21 + k], rr); \
    rr = dppsum64(g##k##b.y); if (lane == 63 && rr != 0.0f) atomicAdd(&sS[10 + 3 * 21 + k], rr); }
    GF(0) GF(1) GF(2) GF(3) GF(4) GF(5) GF(6)
#undef GF
#pragma unroll
    for (int j = 0; j < 14; j++) {
      if (j < FS) {
        float m = (float)((pat >> j) & 1u);
        rr = dppsum64(m * aQa.x); if (lane == 63 && rr != 0.0f) atomicAdd(&sS[10 + 0 * 21 + FBE + j], rr);
        rr = dppsum64(m * aQa.y); if (lane == 63 && rr != 0.0f) atomicAdd(&sS[10 + 1 * 21 + FBE + j], rr);
        rr = dppsum64(m * aQb.x); if (lane == 63 && rr != 0.0f) atomicAdd(&sS[10 + 2 * 21 + FBE + j], rr);
        rr = dppsum64(m * aQb.y); if (lane == 63 && rr != 0.0f) atomicAdd(&sS[10 + 3 * 21 + FBE + j], rr);
      }
    }
  }
  __syncthreads();
  if (tx < SUMS_STRIDE) {
    float v = sS[tx];
    if (v != 0.0f) gatomic(&ws[OFF_SUMS + t * SUMS_STRIDE + tx], v);
  }
}

__global__ __launch_bounds__(BT) void kc(
    const float* W1_2, const float* b1_2, const float* W2_2, const float* b2_2,
    const float* W1_3, const float* b1_3, const float* W2_3, const float* b2_3,
    float* ws) {
  __shared__ float4 tabEX[128], tabS0[128], tabS1[128];
  __shared__ float sS[SUMS_STRIDE];
  int b = blockIdx.x;
  if (b < NSTEP2 * KC_B2) {
    int t = b / KC_B2, sub = b % KC_B2;
    kc_work<21>(t, sub, W1_2, b1_2, W2_2, b2_2, ws, tabEX, tabS0, tabS1, sS);
  } else {
    int b3 = b - NSTEP2 * KC_B2;
    int t = NSTEP2 + b3 / KC_B3, sub = b3 % KC_B3;
    kc_work<20>(t, sub, W1_3, b1_3, W2_3, b2_3, ws, tabEX, tabS0, tabS1, sS);
  }
}

// =================== Kernel D: finalize gradient outputs ===================
__global__ __launch_bounds__(256) void kd(
                   const float* W1_2, const float* b1_2, const float* W2_2, const float* b2_2,
                   const float* W1_3, const float* b1_3, const float* W2_3, const float* b2_3,
                   const float* ws, float* out) {
  __shared__ float sS[NSTEPS * SUMS_STRIDE];
  __shared__ float sk_s[NSTEPS][4], hk_s[NSTEPS][4], pp_s[NSTEPS], s0i_s[NSTEPS];
  int tx = threadIdx.x;
  for (int i = tx; i < NSTEPS * SUMS_STRIDE; i += 256) sS[i] = ws[OFF_SUMS + i];
  __syncthreads();
  if (tx < NSTEPS) {
    int t = tx; int g = (t < NSTEP2) ? 0 : 1; int L = g ? L3 : L2;
    const float* W1 = g ? W1_3 : W1_2;
    const float* W2 = g ? W2_3 : W2_2;
    float p = ws[OFF_PCHAIN + t];
    pp_s[t] = p;
    s0i_s[t] = 1.0f / sS[t * SUMS_STRIDE + 0];
    for (int h = 0; h < 4; h++) {
      float hk = fast_tanh(ws[OFF_KEYB + t * 4 + h] + p * W1[h * (L + 1)]);
      hk_s[t][h] = hk;
      sk_s[t][h] = (1.0f - hk * hk) * W2[h];
    }
  }
  __syncthreads();
  const unsigned* cbp = (const unsigned*)ws;
  for (int o = 33 + tx; o < 223; o += blockDim.x) {
    float val = 0.0f;
    if (o < 130) {
      if (o < 121) {
        int e = o - 33; int h = e / 22, d = e % 22;
        for (int t = 0; t < NSTEP2; t++) {
          float xk = (d == 0) ? pp_s[t] : (float)((cbp[OFF_CB + t] >> (d - 1)) & 1);
          float gs = (d == 0) ? pp_s[t] * sS[t * SUMS_STRIDE + 2 + h]
                              : sS[t * SUMS_STRIDE + 10 + h * 21 + (d - 1)];
          val += sk_s[t][h] * xk - gs * s0i_s[t];
        }
      } else if (o < 125) { int h = o - 121;
        for (int t = 0; t < NSTEP2; t++) val += sk_s[t][h] - sS[t * SUMS_STRIDE + 2 + h] * s0i_s[t];
      } else if (o < 129) { int h = o - 125;
        for (int t = 0; t < NSTEP2; t++) val += hk_s[t][h] - sS[t * SUMS_STRIDE + 6 + h] * s0i_s[t];
      } else {
        for (int t = 0; t < NSTEP2; t++) val += 1.0f - sS[t * SUMS_STRIDE + 1] * s0i_s[t];
      }
    } else {
      if (o < 214) {
        int e = o - 130; int h = e / 21, d = e % 21;
        for (int t = NSTEP2; t < NSTEPS; t++) {
          float xk = (d == 0) ? pp_s[t] : (float)((cbp[OFF_CB + t] >> (d - 1)) & 1);
          float gs = (d == 0) ? pp_s[t] * sS[t * SUMS_STRIDE + 2 + h]
                              : sS[t * SUMS_STRIDE + 10 + h * 21 + (d - 1)];
          val += sk_s[t][h] * xk - gs * s0i_s[t];
        }
      } else if (o < 218) { int h = o - 214;
        for (int t = NSTEP2; t < NSTEPS; t++) val += sk_s[t][h] - sS[t * SUMS_STRIDE + 2 + h] * s0i_s[t];
      } else if (o < 222) { int h = o - 218;
        for (int t = NSTEP2; t < NSTEPS; t++) val += hk_s[t][h] - sS[t * SUMS_STRIDE + 6 + h] * s0i_s[t];
      } else {
        for (int t = NSTEP2; t < NSTEPS; t++) val += 1.0f - sS[t * SUMS_STRIDE + 1] * s0i_s[t];
      }
    }
    out[o] = val;
  }
}

extern "C" void kernel_launch(void* const* d_in, const int* in_sizes, int n_in,
                              void* d_out, int out_size, void* d_ws, size_t ws_size,
                              hipStream_t stream) {
  const float* p0   = (const float*)d_in[0];
  const float* sel  = (const float*)d_in[1];
  const float* W1_2 = (const float*)d_in[2]; const float* b1_2 = (const float*)d_in[3];
  const float* W2_2 = (const float*)d_in[4]; const float* b2_2 = (const float*)d_in[5];
  const float* W1_3 = (const float*)d_in[6]; const float* b1_3 = (const float*)d_in[7];
  const float* W2_3 = (const float*)d_in[8]; const float* b2_3 = (const float*)d_in[9];
  float* out = (float*)d_out;
  float* ws  = (float*)d_ws;
  hipLaunchKernelGGL(kz, dim3(1 + (NPAT2 + NPAT3) / 256), dim3(256), 0, stream,
                     p0, sel, W1_2, b1_2, W1_3, b1_3, ws);
  hipLaunchKernelGGL(ka, dim3(KA_BLOCKS), dim3(BT), 0, stream,
                     W1_2, b1_2, W2_2, b2_2, W1_3, b1_3, W2_3, b2_3, ws);
  hipLaunchKernelGGL(kb, dim3(1), dim3(64), 0, stream, p0,
                     W1_2, b1_2, W2_2, b2_2, W1_3, b1_3, W2_3, b2_3, ws, out);
  hipLaunchKernelGGL(kc, dim3(KC_BLOCKS), dim3(BT), 0, stream,
                     W1_2, b1_2, W2_2, b2_2, W1_3, b1_3, W2_3, b2_3, ws);
  hipLaunchKernelGGL(kd, dim3(1), dim3(256), 0, stream,
                     W1_2, b1_2, W2_2, b2_2, W1_3, b1_3, W2_3, b2_3, ws, out);
}

// Round 15
// 91.705 us; speedup vs baseline: 1.0770x; 1.0770x over previous
//
#include <hip/hip_runtime.h>
#include <cstdint>
#include <cmath>

#define DEV __device__ __forceinline__

constexpr int SEL = 20;
constexpr int NSTEP2 = 10, NSTEP3 = 22, NSTEPS = 32;
constexpr int L2 = SEL + 1;   // 21 bits, group2
constexpr int L3 = SEL;       // 20 bits, group3
constexpr int FBE = 7;        // enumerated low bits
constexpr int FBS2 = L2 - FBE;   // 14
constexpr int FBS3 = L3 - FBE;   // 13
constexpr int BT = 128;          // block threads for ka/kc

typedef float v2f __attribute__((ext_vector_type(2)));

constexpr float K2E = 2.8853900817779268f;   // 2*log2(e)
constexpr float KE  = 1.4426950408889634f;   // log2(e)

struct Binom { unsigned v[22][22]; };
constexpr Binom make_binom() {
  Binom b{};
  for (int n = 0; n < 22; n++) {
    b.v[n][0] = 1;
    for (int k = 1; k < 22; k++)
      b.v[n][k] = (k > n) ? 0u : (k == n ? 1u : b.v[n - 1][k - 1] + b.v[n - 1][k]);
  }
  return b;
}
constexpr Binom BN_H = make_binom();
__device__ constexpr Binom BN = make_binom();

constexpr unsigned ceil64u(unsigned x) { return (x + 63u) & ~63u; }
constexpr int padded_count(int NB) {
  int s = 0;
  for (int k = 0; k <= NB; k++) s += (int)ceil64u(BN_H.v[NB][k]);
  return s;
}
constexpr int NPAT2P = padded_count(FBS2);  // 16896
constexpr int NPAT3P = padded_count(FBS3);  // 8832

// ---- ws layout (float indices) ----
constexpr int OFF_T      = 0;                               // T[2][22][2] = 88 (value, deriv)
constexpr int OFF_SUMS   = OFF_T + 2 * 22 * 2;
constexpr int SUMS_STRIDE = 96;
constexpr int OFF_PCHAIN = OFF_SUMS + NSTEPS * SUMS_STRIDE;
constexpr int OFF_KEYB   = OFF_PCHAIN + 40;
constexpr int OFF_CT     = OFF_KEYB + 128;
constexpr int OFF_CB     = OFF_CT + 32;
constexpr int OFF_NEED   = OFF_CB + 32;
constexpr int OFF_ZEND   = OFF_NEED + 8;
constexpr int OFF_PAT2   = OFF_ZEND;                        // uint[NPAT2P], popc-sorted, 64-padded classes
constexpr int OFF_PAT3   = OFF_PAT2 + NPAT2P;               // uint[NPAT3P]

DEV float fast_tanh(float x) {
  float e = exp2f(x * K2E);
  return 1.0f - 2.0f * __builtin_amdgcn_rcpf(e + 1.0f);
}
DEV float fast_exp(float x) { return exp2f(x * KE); }
DEV void gatomic(float* p, float v) { unsafeAtomicAdd(p, v); }

DEV unsigned gosper(unsigned cmb) {
  unsigned u = cmb & (~cmb + 1u);
  unsigned v = cmb + u;
  return v | ((cmb ^ v) >> (1 + __ffs(u)));
}

// wave64 sum via DPP (verified r12). Total lands in lane 63.
DEV float dppsum64(float x) {
  float f = x;
  f += __int_as_float(__builtin_amdgcn_update_dpp(0, __float_as_int(f), 0x111, 0xf, 0xf, false));
  f += __int_as_float(__builtin_amdgcn_update_dpp(0, __float_as_int(f), 0x112, 0xf, 0xf, false));
  f += __int_as_float(__builtin_amdgcn_update_dpp(0, __float_as_int(f), 0x114, 0xf, 0xf, false));
  f += __int_as_float(__builtin_amdgcn_update_dpp(0, __float_as_int(f), 0x118, 0xf, 0xf, false));
  f += __int_as_float(__builtin_amdgcn_update_dpp(0, __float_as_int(f), 0x142, 0xa, 0xf, false));
  f += __int_as_float(__builtin_amdgcn_update_dpp(0, __float_as_int(f), 0x143, 0xc, 0xf, false));
  return f;
}

template<int CTRL>
DEV float qperm(float x) {
  return __int_as_float(__builtin_amdgcn_update_dpp(0, __float_as_int(x), CTRL, 0xf, 0xf, false));
}

// =================== Kernel Z: init + popc-sorted, 64-padded pattern tables ===================
__global__ void kz(const float* p0, const float* sel,
                   const float* W1_2, const float* b1_2,
                   const float* W1_3, const float* b1_3, float* ws) {
  int tx = threadIdx.x;
  if (blockIdx.x == 0) {
    for (int i = tx; i < OFF_ZEND; i += blockDim.x) ws[i] = 0.0f;
    __syncthreads();
    if (tx < NSTEPS) {
      int t = tx;
      int g = (t < NSTEP2) ? 0 : 1;
      int L = g ? L3 : L2;
      const float* sbase = sel + (g ? (NSTEP2 * L2 + (t - NSTEP2) * L3) : t * L2);
      unsigned cb = 0; int c = 0;
      for (int d = 0; d < L; d++)
        if (sbase[d] > 0.5f) { cb |= 1u << d; c++; }
      ((int*)ws)[OFF_CT + t] = c;
      ((unsigned*)ws)[OFF_CB + t] = cb;
      atomicOr(&((unsigned*)ws)[OFF_NEED + g], 1u << c);
      const float* W1 = g ? W1_3 : W1_2;
      const float* b1 = g ? b1_3 : b1_2;
      for (int h = 0; h < 4; h++) {
        float s = b1[h];
        for (int d = 0; d < L; d++)
          if ((cb >> d) & 1) s += W1[h * (L + 1) + 1 + d];
        ws[OFF_KEYB + t * 4 + h] = s;
      }
      if (tx == 0) ws[OFF_PCHAIN] = p0[0];
    }
  } else {
    int r = (blockIdx.x - 1) * 256 + tx;
    if (r >= NPAT2P + NPAT3P) return;
    int NB, rr, off;
    if (r < NPAT2P) { NB = FBS2; rr = r; off = OFF_PAT2; }
    else            { NB = FBS3; rr = r - NPAT2P; off = OFF_PAT3; }
    unsigned pat = 0xFFFFFFFFu;   // sentinel (padding)
    unsigned base = 0;
    for (int kk = 0; kk <= NB; kk++) {
      unsigned csz = BN.v[NB][kk];
      unsigned psz = (csz + 63u) & ~63u;
      if ((unsigned)rr < base + psz) {
        unsigned local = (unsigned)rr - base;
        if (local < csz) {
          unsigned p2 = 0; int k2 = kk;
          for (int bb = NB - 1; bb >= 0 && k2 > 0; bb--) {
            unsigned cnt = BN.v[bb][k2];
            if (local >= cnt) { p2 |= 1u << bb; local -= cnt; k2--; }
          }
          pat = p2;
        }
        break;
      }
      base += psz;
    }
    ((unsigned*)ws)[off + rr] = pat;
  }
}

// =================== shared tab builder ===================
template<int LL>
DEV void build_tabs(const float* W1, float4 add,
                    float4* tabEX, float4* tabS0, float4* tabS1) {
  constexpr int NS1 = 1 << (LL - 14);
  int tx = threadIdx.x;
  for (int i = tx; i < 256 + NS1; i += BT) {
    if (i < 128) {
      int e = i;
      float s0 = 0, s1 = 0, s2 = 0, s3 = 0;
      for (int j = 0; j < 7; j++) if ((e >> j) & 1) {
        s0 += W1[0 * (LL + 1) + 1 + j]; s1 += W1[1 * (LL + 1) + 1 + j];
        s2 += W1[2 * (LL + 1) + 1 + j]; s3 += W1[3 * (LL + 1) + 1 + j];
      }
      tabEX[e] = make_float4(exp2f(K2E * s0), exp2f(K2E * s1), exp2f(K2E * s2), exp2f(K2E * s3));
    } else if (i < 256) {
      int e = i - 128;
      float s0 = add.x, s1 = add.y, s2 = add.z, s3 = add.w;
      for (int j = 0; j < 7; j++) if ((e >> j) & 1) {
        s0 += W1[0 * (LL + 1) + 1 + 7 + j]; s1 += W1[1 * (LL + 1) + 1 + 7 + j];
        s2 += W1[2 * (LL + 1) + 1 + 7 + j]; s3 += W1[3 * (LL + 1) + 1 + 7 + j];
      }
      tabS0[e] = make_float4(s0, s1, s2, s3);
    } else {
      int e = i - 256;
      float s0 = 0, s1 = 0, s2 = 0, s3 = 0;
      for (int j = 0; j < LL - 14; j++) if ((e >> j) & 1) {
        s0 += W1[0 * (LL + 1) + 1 + 14 + j]; s1 += W1[1 * (LL + 1) + 1 + 14 + j];
        s2 += W1[2 * (LL + 1) + 1 + 14 + j]; s3 += W1[3 * (LL + 1) + 1 + 14 + j];
      }
      tabS1[e] = make_float4(s0, s1, s2, s3);
    }
  }
}

// =================== Kernel A: per-class T0 (value at p=0) + T1 (d/dp) ===================
constexpr int KA_B2 = NPAT2P / BT;  // 132
constexpr int KA_B3 = NPAT3P / BT;  // 69
constexpr int KA_BLOCKS = 22 * KA_B2 + 21 * KA_B3;

template<int LL>
DEV void ka_work(int g, int c, int sub,
                 const float* W1, const float* b1, const float* W2, const float* b2,
                 float* ws, float4* tabEX, float4* tabS0, float4* tabS1, float* sT) {
  constexpr int NS1M = (1 << (LL - 14)) - 1;
  int tx = threadIdx.x;
  const unsigned* pats = ((const unsigned*)ws) + (LL == 21 ? OFF_PAT2 : OFF_PAT3);
  int pcF = __popc(pats[sub * BT]);        // wave-leader popcounts are always valid
  int pcL = __popc(pats[sub * BT + 64]);
  if (c < pcF || c - pcL > FBE) return;
  build_tabs<LL>(W1, make_float4(b1[0], b1[1], b1[2], b1[3]), tabEX, tabS0, tabS1);
  if (tx < 2) sT[tx] = 0.0f;
  __syncthreads();
  unsigned pat = pats[sub * BT + tx];
  int ce = c - __popc(pat);
  int ce_s = __builtin_amdgcn_readfirstlane(ce);
  int trip = (ce_s >= 0 && ce_s <= FBE) ? (int)BN.v[FBE][ce_s] : 0;
  if (trip > 0) {
    float valid = (ce == ce_s) ? 1.0f : 0.0f;
    float4 vS0 = tabS0[pat & 127];
    float4 vS1 = tabS1[(pat >> 7) & NS1M];
    float E0 = exp2f(K2E * (vS0.x + vS1.x));
    float E1 = exp2f(K2E * (vS0.y + vS1.y));
    float E2 = exp2f(K2E * (vS0.z + vS1.z));
    float E3 = exp2f(K2E * (vS0.w + vS1.w));
    float a0 = W1[0], a1 = W1[LL + 1], a2 = W1[2 * (LL + 1)], a3 = W1[3 * (LL + 1)];
    float w0 = W2[0], w1 = W2[1], w2 = W2[2], w3 = W2[3];
    float W0 = b2[0] + w0 + w1 + w2 + w3;
    float m0 = -2.0f * w0, m1 = -2.0f * w1, m2 = -2.0f * w2, m3 = -2.0f * w3;
    float A0 = 4.0f * w0 * a0, A1 = 4.0f * w1 * a1, A2 = 4.0f * w2 * a2, A3 = 4.0f * w3 * a3;
    float acc0 = 0.0f, accD = 0.0f;
    unsigned ivs = (1u << ce_s) - 1u;
    float4 tE = tabEX[ivs & 127];
#pragma unroll 1
    for (int k = 0; k < trip; k++) {
      float4 cur = tE;
      ivs = gosper(ivs);
      tE = tabEX[ivs & 127];
      float r0 = __builtin_amdgcn_rcpf(fmaf(cur.x, E0, 1.0f));
      float r1 = __builtin_amdgcn_rcpf(fmaf(cur.y, E1, 1.0f));
      float r2 = __builtin_amdgcn_rcpf(fmaf(cur.z, E2, 1.0f));
      float r3 = __builtin_amdgcn_rcpf(fmaf(cur.w, E3, 1.0f));
      float outv = W0;
      outv = fmaf(m0, r0, outv); outv = fmaf(m1, r1, outv);
      outv = fmaf(m2, r2, outv); outv = fmaf(m3, r3, outv);
      float e = exp2f(KE * outv) * valid;
      float u0 = fmaf(-r0, r0, r0), u1 = fmaf(-r1, r1, r1);
      float u2 = fmaf(-r2, r2, r2), u3 = fmaf(-r3, r3, r3);
      float s = A0 * u0; s = fmaf(A1, u1, s); s = fmaf(A2, u2, s); s = fmaf(A3, u3, s);
      acc0 += e;
      accD = fmaf(e, s, accD);
    }
    float v0 = dppsum64(acc0), v1 = dppsum64(accD);
    if ((tx & 63) == 63) {
      if (v0 != 0.0f) atomicAdd(&sT[0], v0);
      if (v1 != 0.0f) atomicAdd(&sT[1], v1);
    }
  }
  __syncthreads();
  if (tx < 2) {
    float v = sT[tx];
    if (v != 0.0f) gatomic(&ws[OFF_T + (g * 22 + c) * 2 + tx], v);
  }
}

__global__ __launch_bounds__(BT) void ka(
    const float* W1_2, const float* b1_2, const float* W2_2, const float* b2_2,
    const float* W1_3, const float* b1_3, const float* W2_3, const float* b2_3,
    float* ws) {
  __shared__ float4 tabEX[128], tabS0[128], tabS1[128];
  __shared__ float sT[2];
  int b = blockIdx.x;
  int g, c, sub;
  if (b < 22 * KA_B2) { g = 0; c = b / KA_B2; sub = b % KA_B2; }
  else { int b3 = b - 22 * KA_B2; g = 1; c = b3 / KA_B3; sub = b3 % KA_B3; }
  unsigned need = ((const unsigned*)ws)[OFF_NEED + g];
  if (!((need >> c) & 1)) return;
  if (g == 0) ka_work<21>(0, c, sub, W1_2, b1_2, W2_2, b2_2, ws, tabEX, tabS0, tabS1, sT);
  else        ka_work<20>(1, c, sub, W1_3, b1_3, W2_3, b2_3, ws, tabEX, tabS0, tabS1, sT);
}

// =================== Kernel B: prob chain; Se(p) = T0 * exp(p*T1/T0) ===================
__global__ __launch_bounds__(64) void kb(const float* p0in,
                   const float* W1_2, const float* b1_2, const float* W2_2, const float* b2_2,
                   const float* W1_3, const float* b1_3, const float* W2_3, const float* b2_3,
                   float* ws, float* out) {
  __shared__ float sT[2 * 22 * 2];
  __shared__ float sKEYB[128], sW1c0[8], sW2[8], sB2[2];
  __shared__ int sCT[32];
  int lane = threadIdx.x;
  for (int i = lane; i < 2 * 22 * 2; i += 64) sT[i] = ws[OFF_T + i];
  for (int i = lane; i < 128; i += 64) sKEYB[i] = ws[OFF_KEYB + i];
  if (lane < 32) sCT[lane] = ((const int*)ws)[OFF_CT + lane];
  if (lane < 4) {
    sW1c0[lane]     = W1_2[lane * (L2 + 1)];
    sW1c0[4 + lane] = W1_3[lane * (L3 + 1)];
    sW2[lane]     = W2_2[lane];
    sW2[4 + lane] = W2_3[lane];
  }
  if (lane == 0) { sB2[0] = b2_2[0]; sB2[1] = b2_3[0]; }
  __syncthreads();
  float p = p0in[0];
  if (lane == 0) out[0] = p;
  int h = lane & 3;
#pragma unroll 1
  for (int tt = 0; tt < NSTEPS; tt++) {
    int g = (tt < NSTEP2) ? 0 : 1;
    int c = sCT[tt];
    float hk = fast_tanh(sKEYB[tt * 4 + h] + p * sW1c0[g * 4 + h]);
    float contrib = sW2[g * 4 + h] * hk;
    contrib += qperm<0xB1>(contrib);
    contrib += qperm<0x4E>(contrib);
    float outk = sB2[g] + contrib;
    float T0 = sT[(g * 22 + c) * 2 + 0], T1v = sT[(g * 22 + c) * 2 + 1];
    float Se = T0 * fast_exp(p * (T1v / T0));
    p = fast_exp(outk) / Se;
    if (lane == 0) { out[1 + tt] = p; ws[OFF_PCHAIN + 1 + tt] = p; }
  }
}

// =================== Kernel C: scalar-iv enumeration, branchy grads ===================
constexpr int KC_B2 = NPAT2P / BT;   // 132
constexpr int KC_B3 = NPAT3P / BT;   // 69
constexpr int KC_BLOCKS = NSTEP2 * KC_B2 + NSTEP3 * KC_B3;

template<int LL>
DEV void kc_work(int t, int sub,
                 const float* W1, const float* b1, const float* W2, const float* b2,
                 float* ws, float4* tabEX, float4* tabS0, float4* tabS1, float* sS) {
  constexpr int FS = LL - FBE;
  constexpr int NS1M = (1 << (LL - 14)) - 1;
  int tx = threadIdx.x;
  int c = ((const int*)ws)[OFF_CT + t];
  const unsigned* pats = ((const unsigned*)ws) + (LL == 21 ? OFF_PAT2 : OFF_PAT3);
  int pcF = __popc(pats[sub * BT]);
  int pcL = __popc(pats[sub * BT + 64]);
  if (c < pcF || c - pcL > FBE) return;
  float p = ws[OFF_PCHAIN + t];
  float4 add = make_float4(b1[0] + p * W1[0 * (LL + 1)], b1[1] + p * W1[1 * (LL + 1)],
                           b1[2] + p * W1[2 * (LL + 1)], b1[3] + p * W1[3 * (LL + 1)]);
  build_tabs<LL>(W1, add, tabEX, tabS0, tabS1);
  if (tx < SUMS_STRIDE) sS[tx] = 0.0f;
  __syncthreads();
  unsigned pat = pats[sub * BT + tx];
  int ce = c - __popc(pat);
  int ce_s = __builtin_amdgcn_readfirstlane(ce);
  int trip = (ce_s >= 0 && ce_s <= FBE) ? (int)BN.v[FBE][ce_s] : 0;
  if (trip > 0) {
    float valid = (ce == ce_s) ? 1.0f : 0.0f;
    float4 vS0 = tabS0[pat & 127];
    float4 vS1 = tabS1[(pat >> 7) & NS1M];
    float E0 = exp2f(K2E * (vS0.x + vS1.x));
    float E1 = exp2f(K2E * (vS0.y + vS1.y));
    float E2 = exp2f(K2E * (vS0.z + vS1.z));
    float E3 = exp2f(K2E * (vS0.w + vS1.w));
    float w0 = W2[0], w1 = W2[1], w2 = W2[2], w3 = W2[3];
    float W0 = b2[0] + w0 + w1 + w2 + w3;
    float m0 = -2.0f * w0, m1 = -2.0f * w1, m2 = -2.0f * w2, m3 = -2.0f * w3;
    float M0 = 4.0f * w0, M1 = 4.0f * w1, M2 = 4.0f * w2, M3 = 4.0f * w3;

    float aE = 0.0f, aW = 0.0f;
    v2f aQa = {0, 0}, aQb = {0, 0}, ORa = {0, 0}, ORb = {0, 0};
#define G_DECL(k) v2f g##k##a = {0, 0}, g##k##b = {0, 0};
    G_DECL(0) G_DECL(1) G_DECL(2) G_DECL(3) G_DECL(4) G_DECL(5) G_DECL(6)
#undef G_DECL

    unsigned ivs = (1u << ce_s) - 1u;
    float4 tE = tabEX[ivs & 127];
#pragma unroll 1
    for (int k = 0; k < trip; k++) {
      float4 cur = tE;
      unsigned ivc = ivs;
      ivs = gosper(ivs);
      tE = tabEX[ivs & 127];
      float r0 = __builtin_amdgcn_rcpf(fmaf(cur.x, E0, 1.0f));
      float r1 = __builtin_amdgcn_rcpf(fmaf(cur.y, E1, 1.0f));
      float r2 = __builtin_amdgcn_rcpf(fmaf(cur.z, E2, 1.0f));
      float r3 = __builtin_amdgcn_rcpf(fmaf(cur.w, E3, 1.0f));
      float outv = W0;
      outv = fmaf(m0, r0, outv); outv = fmaf(m1, r1, outv);
      outv = fmaf(m2, r2, outv); outv = fmaf(m3, r3, outv);
      float e = exp2f(KE * outv) * valid;
      outv *= valid;
      float u0 = fmaf(-r0, r0, r0), u1 = fmaf(-r1, r1, r1);
      float u2 = fmaf(-r2, r2, r2), u3 = fmaf(-r3, r3, r3);
      float q0 = outv * (M0 * u0), q1 = outv * (M1 * u1);
      float q2 = outv * (M2 * u2), q3 = outv * (M3 * u3);
      v2f qa = {q0, q1}, qb = {q2, q3};
      aE += e; aW += outv;
      aQa += qa; aQb += qb;
      ORa += (v2f){outv * r0, outv * r1};
      ORb += (v2f){outv * r2, outv * r3};
#define G_UPD(k) if (ivc & (1u << k)) { g##k##a += qa; g##k##b += qb; }
      G_UPD(0) G_UPD(1) G_UPD(2) G_UPD(3) G_UPD(4) G_UPD(5) G_UPD(6)
#undef G_UPD
    }
    // per-lane aWH_h = aW - 2*OR_h
    v2f aWHa = {aW - 2.0f * ORa.x, aW - 2.0f * ORa.y};
    v2f aWHb = {aW - 2.0f * ORb.x, aW - 2.0f * ORb.y};

    int lane = tx & 63;
    float rr;
    rr = dppsum64(aE); if (lane == 63 && rr != 0.0f) atomicAdd(&sS[0], rr);
    rr = dppsum64(aW); if (lane == 63 && rr != 0.0f) atomicAdd(&sS[1], rr);
    rr = dppsum64(aQa.x); if (lane == 63 && rr != 0.0f) atomicAdd(&sS[2], rr);
    rr = dppsum64(aQa.y); if (lane == 63 && rr != 0.0f) atomicAdd(&sS[3], rr);
    rr = dppsum64(aQb.x); if (lane == 63 && rr != 0.0f) atomicAdd(&sS[4], rr);
    rr = dppsum64(aQb.y); if (lane == 63 && rr != 0.0f) atomicAdd(&sS[5], rr);
    rr = dppsum64(aWHa.x); if (lane == 63 && rr != 0.0f) atomicAdd(&sS[6], rr);
    rr = dppsum64(aWHa.y); if (lane == 63 && rr != 0.0f) atomicAdd(&sS[7], rr);
    rr = dppsum64(aWHb.x); if (lane == 63 && rr != 0.0f) atomicAdd(&sS[8], rr);
    rr = dppsum64(aWHb.y); if (lane == 63 && rr != 0.0f) atomicAdd(&sS[9], rr);
#define GF(k) { \
    rr = dppsum64(g##k##a.x); if (lane == 63 && rr != 0.0f) atomicAdd(&sS[10 + 0 * 21 + k], rr); \
    rr = dppsum64(g##k##a.y); if (lane == 63 && rr != 0.0f) atomicAdd(&sS[10 + 1 * 21 + k], rr); \
    rr = dppsum64(g##k##b.x); if (lane == 63 && rr != 0.0f) atomicAdd(&sS[10 + 2 * 21 + k], rr); \
    rr = dppsum64(g##k##b.y); if (lane == 63 && rr != 0.0f) atomicAdd(&sS[10 + 3 * 21 + k], rr); }
    GF(0) GF(1) GF(2) GF(3) GF(4) GF(5) GF(6)
#undef GF
#pragma unroll
    for (int j = 0; j < 14; j++) {
      if (j < FS) {
        float m = (float)((pat >> j) & 1u);   // sentinel lanes contribute 0 anyway (aQ==0)
        rr = dppsum64(m * aQa.x); if (lane == 63 && rr != 0.0f) atomicAdd(&sS[10 + 0 * 21 + FBE + j], rr);
        rr = dppsum64(m * aQa.y); if (lane == 63 && rr != 0.0f) atomicAdd(&sS[10 + 1 * 21 + FBE + j], rr);
        rr = dppsum64(m * aQb.x); if (lane == 63 && rr != 0.0f) atomicAdd(&sS[10 + 2 * 21 + FBE + j], rr);
        rr = dppsum64(m * aQb.y); if (lane == 63 && rr != 0.0f) atomicAdd(&sS[10 + 3 * 21 + FBE + j], rr);
      }
    }
  }
  __syncthreads();
  if (tx < SUMS_STRIDE) {
    float v = sS[tx];
    if (v != 0.0f) gatomic(&ws[OFF_SUMS + t * SUMS_STRIDE + tx], v);
  }
}

__global__ __launch_bounds__(BT) void kc(
    const float* W1_2, const float* b1_2, const float* W2_2, const float* b2_2,
    const float* W1_3, const float* b1_3, const float* W2_3, const float* b2_3,
    float* ws) {
  __shared__ float4 tabEX[128], tabS0[128], tabS1[128];
  __shared__ float sS[SUMS_STRIDE];
  int b = blockIdx.x;
  if (b < NSTEP2 * KC_B2) {
    int t = b / KC_B2, sub = b % KC_B2;
    kc_work<21>(t, sub, W1_2, b1_2, W2_2, b2_2, ws, tabEX, tabS0, tabS1, sS);
  } else {
    int b3 = b - NSTEP2 * KC_B2;
    int t = NSTEP2 + b3 / KC_B3, sub = b3 % KC_B3;
    kc_work<20>(t, sub, W1_3, b1_3, W2_3, b2_3, ws, tabEX, tabS0, tabS1, sS);
  }
}

// =================== Kernel D: finalize gradient outputs ===================
__global__ __launch_bounds__(256) void kd(
                   const float* W1_2, const float* b1_2, const float* W2_2, const float* b2_2,
                   const float* W1_3, const float* b1_3, const float* W2_3, const float* b2_3,
                   const float* ws, float* out) {
  __shared__ float sS[NSTEPS * SUMS_STRIDE];
  __shared__ float sk_s[NSTEPS][4], hk_s[NSTEPS][4], pp_s[NSTEPS], s0i_s[NSTEPS];
  int tx = threadIdx.x;
  for (int i = tx; i < NSTEPS * SUMS_STRIDE; i += 256) sS[i] = ws[OFF_SUMS + i];
  __syncthreads();
  if (tx < NSTEPS) {
    int t = tx; int g = (t < NSTEP2) ? 0 : 1; int L = g ? L3 : L2;
    const float* W1 = g ? W1_3 : W1_2;
    const float* W2 = g ? W2_3 : W2_2;
    float p = ws[OFF_PCHAIN + t];
    pp_s[t] = p;
    s0i_s[t] = 1.0f / sS[t * SUMS_STRIDE + 0];
    for (int h = 0; h < 4; h++) {
      float hk = fast_tanh(ws[OFF_KEYB + t * 4 + h] + p * W1[h * (L + 1)]);
      hk_s[t][h] = hk;
      sk_s[t][h] = (1.0f - hk * hk) * W2[h];
    }
  }
  __syncthreads();
  const unsigned* cbp = (const unsigned*)ws;
  for (int o = 33 + tx; o < 223; o += blockDim.x) {
    float val = 0.0f;
    if (o < 130) {
      if (o < 121) {
        int e = o - 33; int h = e / 22, d = e % 22;
        for (int t = 0; t < NSTEP2; t++) {
          float xk = (d == 0) ? pp_s[t] : (float)((cbp[OFF_CB + t] >> (d - 1)) & 1);
          float gs = (d == 0) ? pp_s[t] * sS[t * SUMS_STRIDE + 2 + h]
                              : sS[t * SUMS_STRIDE + 10 + h * 21 + (d - 1)];
          val += sk_s[t][h] * xk - gs * s0i_s[t];
        }
      } else if (o < 125) { int h = o - 121;
        for (int t = 0; t < NSTEP2; t++) val += sk_s[t][h] - sS[t * SUMS_STRIDE + 2 + h] * s0i_s[t];
      } else if (o < 129) { int h = o - 125;
        for (int t = 0; t < NSTEP2; t++) val += hk_s[t][h] - sS[t * SUMS_STRIDE + 6 + h] * s0i_s[t];
      } else {
        for (int t = 0; t < NSTEP2; t++) val += 1.0f - sS[t * SUMS_STRIDE + 1] * s0i_s[t];
      }
    } else {
      if (o < 214) {
        int e = o - 130; int h = e / 21, d = e % 21;
        for (int t = NSTEP2; t < NSTEPS; t++) {
          float xk = (d == 0) ? pp_s[t] : (float)((cbp[OFF_CB + t] >> (d - 1)) & 1);
          float gs = (d == 0) ? pp_s[t] * sS[t * SUMS_STRIDE + 2 + h]
                              : sS[t * SUMS_STRIDE + 10 + h * 21 + (d - 1)];
          val += sk_s[t][h] * xk - gs * s0i_s[t];
        }
      } else if (o < 218) { int h = o - 214;
        for (int t = NSTEP2; t < NSTEPS; t++) val += sk_s[t][h] - sS[t * SUMS_STRIDE + 2 + h] * s0i_s[t];
      } else if (o < 222) { int h = o - 218;
        for (int t = NSTEP2; t < NSTEPS; t++) val += hk_s[t][h] - sS[t * SUMS_STRIDE + 6 + h] * s0i_s[t];
      } else {
        for (int t = NSTEP2; t < NSTEPS; t++) val += 1.0f - sS[t * SUMS_STRIDE + 1] * s0i_s[t];
      }
    }
    out[o] = val;
  }
}

extern "C" void kernel_launch(void* const* d_in, const int* in_sizes, int n_in,
                              void* d_out, int out_size, void* d_ws, size_t ws_size,
                              hipStream_t stream) {
  const float* p0   = (const float*)d_in[0];
  const float* sel  = (const float*)d_in[1];
  const float* W1_2 = (const float*)d_in[2]; const float* b1_2 = (const float*)d_in[3];
  const float* W2_2 = (const float*)d_in[4]; const float* b2_2 = (const float*)d_in[5];
  const float* W1_3 = (const float*)d_in[6]; const float* b1_3 = (const float*)d_in[7];
  const float* W2_3 = (const float*)d_in[8]; const float* b2_3 = (const float*)d_in[9];
  float* out = (float*)d_out;
  float* ws  = (float*)d_ws;
  hipLaunchKernelGGL(kz, dim3(1 + (NPAT2P + NPAT3P + 255) / 256), dim3(256), 0, stream,
                     p0, sel, W1_2, b1_2, W1_3, b1_3, ws);
  hipLaunchKernelGGL(ka, dim3(KA_BLOCKS), dim3(BT), 0, stream,
                     W1_2, b1_2, W2_2, b2_2, W1_3, b1_3, W2_3, b2_3, ws);
  hipLaunchKernelGGL(kb, dim3(1), dim3(64), 0, stream, p0,
                     W1_2, b1_2, W2_2, b2_2, W1_3, b1_3, W2_3, b2_3, ws, out);
  hipLaunchKernelGGL(kc, dim3(KC_BLOCKS), dim3(BT), 0, stream,
                     W1_2, b1_2, W2_2, b2_2, W1_3, b1_3, W2_3, b2_3, ws);
  hipLaunchKernelGGL(kd, dim3(1), dim3(256), 0, stream,
                     W1_2, b1_2, W2_2, b2_2, W1_3, b1_3, W2_3, b2_3, ws, out);
}

// Round 16
// 72.391 us; speedup vs baseline: 1.3643x; 1.2668x over previous
//
#include <hip/hip_runtime.h>
#include <cstdint>
#include <cmath>

#define DEV __device__ __forceinline__

constexpr int SEL = 20;
constexpr int NSTEP2 = 10, NSTEP3 = 22, NSTEPS = 32;
constexpr int L2 = SEL + 1;   // 21 bits, group2
constexpr int L3 = SEL;       // 20 bits, group3
constexpr int FBE = 7;        // enumerated low bits
constexpr int FBS2 = L2 - FBE;   // 14
constexpr int FBS3 = L3 - FBE;   // 13
constexpr int BT = 128;          // block threads for kc

typedef float v2f __attribute__((ext_vector_type(2)));

constexpr float K2E = 2.8853900817779268f;   // 2*log2(e)
constexpr float KE  = 1.4426950408889634f;   // log2(e)

struct Binom { unsigned v[22][22]; };
constexpr Binom make_binom() {
  Binom b{};
  for (int n = 0; n < 22; n++) {
    b.v[n][0] = 1;
    for (int k = 1; k < 22; k++)
      b.v[n][k] = (k > n) ? 0u : (k == n ? 1u : b.v[n - 1][k - 1] + b.v[n - 1][k]);
  }
  return b;
}
constexpr Binom BN_H = make_binom();
__device__ constexpr Binom BN = make_binom();

constexpr unsigned ceil64u(unsigned x) { return (x + 63u) & ~63u; }
constexpr int padded_count(int NB) {
  int s = 0;
  for (int k = 0; k <= NB; k++) s += (int)ceil64u(BN_H.v[NB][k]);
  return s;
}
constexpr int NPAT2P = padded_count(FBS2);  // 16896
constexpr int NPAT3P = padded_count(FBS3);  // 8832

// ---- ws layout (float indices) ----
constexpr int SUMS_STRIDE = 96;             // [0]=Se [1]=Sw [2..5]=Sws [6..9]=Swh [10+h*21+d]=GW1
constexpr int OFF_SUMS   = 0;               // 32 * 96
constexpr int OFF_KEYB   = OFF_SUMS + NSTEPS * SUMS_STRIDE;  // 128
constexpr int OFF_CT     = OFF_KEYB + 128;  // int[32]
constexpr int OFF_CB     = OFF_CT + 32;     // uint[32]
constexpr int OFF_REP    = OFF_CB + 32;     // int[32]
constexpr int OFF_ZEND   = OFF_REP + 32;
constexpr int OFF_PAT2   = OFF_ZEND;                        // uint[NPAT2P]
constexpr int OFF_PAT3   = OFF_PAT2 + NPAT2P;               // uint[NPAT3P]

DEV float fast_tanh(float x) {
  float e = exp2f(x * K2E);
  return 1.0f - 2.0f * __builtin_amdgcn_rcpf(e + 1.0f);
}
DEV float fast_exp(float x) { return exp2f(x * KE); }
DEV void gatomic(float* p, float v) { unsafeAtomicAdd(p, v); }

DEV unsigned gosper(unsigned cmb) {
  unsigned u = cmb & (~cmb + 1u);
  unsigned v = cmb + u;
  return v | ((cmb ^ v) >> (1 + __ffs(u)));
}

// wave64 sum via DPP (verified r12). Total lands in lane 63.
DEV float dppsum64(float x) {
  float f = x;
  f += __int_as_float(__builtin_amdgcn_update_dpp(0, __float_as_int(f), 0x111, 0xf, 0xf, false));
  f += __int_as_float(__builtin_amdgcn_update_dpp(0, __float_as_int(f), 0x112, 0xf, 0xf, false));
  f += __int_as_float(__builtin_amdgcn_update_dpp(0, __float_as_int(f), 0x114, 0xf, 0xf, false));
  f += __int_as_float(__builtin_amdgcn_update_dpp(0, __float_as_int(f), 0x118, 0xf, 0xf, false));
  f += __int_as_float(__builtin_amdgcn_update_dpp(0, __float_as_int(f), 0x142, 0xa, 0xf, false));
  f += __int_as_float(__builtin_amdgcn_update_dpp(0, __float_as_int(f), 0x143, 0xc, 0xf, false));
  return f;
}

// =================== Kernel Z: init + rep map + popc-sorted padded pattern tables ===================
__global__ void kz(const float* p0, const float* sel,
                   const float* W1_2, const float* b1_2,
                   const float* W1_3, const float* b1_3, float* ws) {
  int tx = threadIdx.x;
  if (blockIdx.x == 0) {
    __shared__ int sc[NSTEPS];
    for (int i = tx; i < OFF_ZEND; i += blockDim.x) ws[i] = 0.0f;
    __syncthreads();
    if (tx < NSTEPS) {
      int t = tx;
      int g = (t < NSTEP2) ? 0 : 1;
      int L = g ? L3 : L2;
      const float* sbase = sel + (g ? (NSTEP2 * L2 + (t - NSTEP2) * L3) : t * L2);
      unsigned cb = 0; int c = 0;
      for (int d = 0; d < L; d++)
        if (sbase[d] > 0.5f) { cb |= 1u << d; c++; }
      sc[t] = c;
      ((int*)ws)[OFF_CT + t] = c;
      ((unsigned*)ws)[OFF_CB + t] = cb;
      const float* W1 = g ? W1_3 : W1_2;
      const float* b1 = g ? b1_3 : b1_2;
      for (int h = 0; h < 4; h++) {
        float s = b1[h];
        for (int d = 0; d < L; d++)
          if ((cb >> d) & 1) s += W1[h * (L + 1) + 1 + d];
        ws[OFF_KEYB + t * 4 + h] = s;
      }
    }
    __syncthreads();
    if (tx < NSTEPS) {
      int r = tx;
      int start = (tx == 0) ? 0 : ((tx < NSTEP2) ? 1 : NSTEP2);
      for (int u = start; u < tx; u++)
        if (sc[u] == sc[tx]) { r = u; break; }
      ((int*)ws)[OFF_REP + tx] = r;
    }
  } else {
    int r = (blockIdx.x - 1) * 256 + tx;
    if (r >= NPAT2P + NPAT3P) return;
    int NB, rr, off;
    if (r < NPAT2P) { NB = FBS2; rr = r; off = OFF_PAT2; }
    else            { NB = FBS3; rr = r - NPAT2P; off = OFF_PAT3; }
    unsigned pat = 0xFFFFFFFFu;   // sentinel (padding)
    unsigned base = 0;
    for (int kk = 0; kk <= NB; kk++) {
      unsigned csz = BN.v[NB][kk];
      unsigned psz = (csz + 63u) & ~63u;
      if ((unsigned)rr < base + psz) {
        unsigned local = (unsigned)rr - base;
        if (local < csz) {
          unsigned p2 = 0; int k2 = kk;
          for (int bb = NB - 1; bb >= 0 && k2 > 0; bb--) {
            unsigned cnt = BN.v[bb][k2];
            if (local >= cnt) { p2 |= 1u << bb; local -= cnt; k2--; }
          }
          pat = p2;
        }
        break;
      }
      base += psz;
    }
    ((unsigned*)ws)[off + rr] = pat;
  }
}

// =================== shared tab builder ===================
template<int LL>
DEV void build_tabs(const float* W1, float4 add,
                    float4* tabEX, float4* tabS0, float4* tabS1) {
  constexpr int NS1 = 1 << (LL - 14);
  int tx = threadIdx.x;
  for (int i = tx; i < 256 + NS1; i += BT) {
    if (i < 128) {
      int e = i;
      float s0 = 0, s1 = 0, s2 = 0, s3 = 0;
      for (int j = 0; j < 7; j++) if ((e >> j) & 1) {
        s0 += W1[0 * (LL + 1) + 1 + j]; s1 += W1[1 * (LL + 1) + 1 + j];
        s2 += W1[2 * (LL + 1) + 1 + j]; s3 += W1[3 * (LL + 1) + 1 + j];
      }
      tabEX[e] = make_float4(exp2f(K2E * s0), exp2f(K2E * s1), exp2f(K2E * s2), exp2f(K2E * s3));
    } else if (i < 256) {
      int e = i - 128;
      float s0 = add.x, s1 = add.y, s2 = add.z, s3 = add.w;
      for (int j = 0; j < 7; j++) if ((e >> j) & 1) {
        s0 += W1[0 * (LL + 1) + 1 + 7 + j]; s1 += W1[1 * (LL + 1) + 1 + 7 + j];
        s2 += W1[2 * (LL + 1) + 1 + 7 + j]; s3 += W1[3 * (LL + 1) + 1 + 7 + j];
      }
      tabS0[e] = make_float4(s0, s1, s2, s3);
    } else {
      int e = i - 256;
      float s0 = 0, s1 = 0, s2 = 0, s3 = 0;
      for (int j = 0; j < LL - 14; j++) if ((e >> j) & 1) {
        s0 += W1[0 * (LL + 1) + 1 + 14 + j]; s1 += W1[1 * (LL + 1) + 1 + 14 + j];
        s2 += W1[2 * (LL + 1) + 1 + 14 + j]; s3 += W1[3 * (LL + 1) + 1 + 14 + j];
      }
      tabS1[e] = make_float4(s0, s1, s2, s3);
    }
  }
}

// =================== Kernel C: per-representative-class enumeration ===================
constexpr int KC_B2 = NPAT2P / BT;   // 132
constexpr int KC_B3 = NPAT3P / BT;   // 69
constexpr int KC_BLOCKS = NSTEP2 * KC_B2 + NSTEP3 * KC_B3;

template<int LL>
DEV void kc_work(int t, int sub, float pval,
                 const float* W1, const float* b1, const float* W2, const float* b2,
                 float* ws, float4* tabEX, float4* tabS0, float4* tabS1, float* sS) {
  constexpr int FS = LL - FBE;
  constexpr int NS1M = (1 << (LL - 14)) - 1;
  int tx = threadIdx.x;
  int c = ((const int*)ws)[OFF_CT + t];
  const unsigned* pats = ((const unsigned*)ws) + (LL == 21 ? OFF_PAT2 : OFF_PAT3);
  int pcF = __popc(pats[sub * BT]);        // wave-leader popcounts always valid (64-aligned classes)
  int pcL = __popc(pats[sub * BT + 64]);
  if (c < pcF || c - pcL > FBE) return;
  float4 add = make_float4(b1[0] + pval * W1[0 * (LL + 1)], b1[1] + pval * W1[1 * (LL + 1)],
                           b1[2] + pval * W1[2 * (LL + 1)], b1[3] + pval * W1[3 * (LL + 1)]);
  build_tabs<LL>(W1, add, tabEX, tabS0, tabS1);
  if (tx < SUMS_STRIDE) sS[tx] = 0.0f;
  __syncthreads();
  unsigned pat = pats[sub * BT + tx];
  int ce = c - __popc(pat);
  int ce_s = __builtin_amdgcn_readfirstlane(ce);
  int trip = (ce_s >= 0 && ce_s <= FBE) ? (int)BN.v[FBE][ce_s] : 0;
  if (trip > 0) {
    float valid = (ce == ce_s) ? 1.0f : 0.0f;
    float4 vS0 = tabS0[pat & 127];
    float4 vS1 = tabS1[(pat >> 7) & NS1M];
    float E0 = exp2f(K2E * (vS0.x + vS1.x));
    float E1 = exp2f(K2E * (vS0.y + vS1.y));
    float E2 = exp2f(K2E * (vS0.z + vS1.z));
    float E3 = exp2f(K2E * (vS0.w + vS1.w));
    float w0 = W2[0], w1 = W2[1], w2 = W2[2], w3 = W2[3];
    float W0 = b2[0] + w0 + w1 + w2 + w3;
    float m0 = -2.0f * w0, m1 = -2.0f * w1, m2 = -2.0f * w2, m3 = -2.0f * w3;
    float M0 = 4.0f * w0, M1 = 4.0f * w1, M2 = 4.0f * w2, M3 = 4.0f * w3;

    float aE = 0.0f, aW = 0.0f;
    v2f aQa = {0, 0}, aQb = {0, 0}, ORa = {0, 0}, ORb = {0, 0};
#define G_DECL(k) v2f g##k##a = {0, 0}, g##k##b = {0, 0};
    G_DECL(0) G_DECL(1) G_DECL(2) G_DECL(3) G_DECL(4) G_DECL(5) G_DECL(6)
#undef G_DECL

    unsigned ivs = (1u << ce_s) - 1u;
    float4 tE = tabEX[ivs & 127];
#pragma unroll 1
    for (int k = 0; k < trip; k++) {
      float4 cur = tE;
      unsigned ivc = ivs;
      ivs = gosper(ivs);
      tE = tabEX[ivs & 127];
      float r0 = __builtin_amdgcn_rcpf(fmaf(cur.x, E0, 1.0f));
      float r1 = __builtin_amdgcn_rcpf(fmaf(cur.y, E1, 1.0f));
      float r2 = __builtin_amdgcn_rcpf(fmaf(cur.z, E2, 1.0f));
      float r3 = __builtin_amdgcn_rcpf(fmaf(cur.w, E3, 1.0f));
      float outv = W0;
      outv = fmaf(m0, r0, outv); outv = fmaf(m1, r1, outv);
      outv = fmaf(m2, r2, outv); outv = fmaf(m3, r3, outv);
      float e = exp2f(KE * outv) * valid;
      outv *= valid;
      float u0 = fmaf(-r0, r0, r0), u1 = fmaf(-r1, r1, r1);
      float u2 = fmaf(-r2, r2, r2), u3 = fmaf(-r3, r3, r3);
      float q0 = outv * (M0 * u0), q1 = outv * (M1 * u1);
      float q2 = outv * (M2 * u2), q3 = outv * (M3 * u3);
      v2f qa = {q0, q1}, qb = {q2, q3};
      aE += e; aW += outv;
      aQa += qa; aQb += qb;
      ORa += (v2f){outv * r0, outv * r1};
      ORb += (v2f){outv * r2, outv * r3};
#define G_UPD(k) if (ivc & (1u << k)) { g##k##a += qa; g##k##b += qb; }
      G_UPD(0) G_UPD(1) G_UPD(2) G_UPD(3) G_UPD(4) G_UPD(5) G_UPD(6)
#undef G_UPD
    }
    v2f aWHa = {aW - 2.0f * ORa.x, aW - 2.0f * ORa.y};
    v2f aWHb = {aW - 2.0f * ORb.x, aW - 2.0f * ORb.y};

    int lane = tx & 63;
    float rr;
    rr = dppsum64(aE); if (lane == 63 && rr != 0.0f) atomicAdd(&sS[0], rr);
    rr = dppsum64(aW); if (lane == 63 && rr != 0.0f) atomicAdd(&sS[1], rr);
    rr = dppsum64(aQa.x); if (lane == 63 && rr != 0.0f) atomicAdd(&sS[2], rr);
    rr = dppsum64(aQa.y); if (lane == 63 && rr != 0.0f) atomicAdd(&sS[3], rr);
    rr = dppsum64(aQb.x); if (lane == 63 && rr != 0.0f) atomicAdd(&sS[4], rr);
    rr = dppsum64(aQb.y); if (lane == 63 && rr != 0.0f) atomicAdd(&sS[5], rr);
    rr = dppsum64(aWHa.x); if (lane == 63 && rr != 0.0f) atomicAdd(&sS[6], rr);
    rr = dppsum64(aWHa.y); if (lane == 63 && rr != 0.0f) atomicAdd(&sS[7], rr);
    rr = dppsum64(aWHb.x); if (lane == 63 && rr != 0.0f) atomicAdd(&sS[8], rr);
    rr = dppsum64(aWHb.y); if (lane == 63 && rr != 0.0f) atomicAdd(&sS[9], rr);
#define GF(k) { \
    rr = dppsum64(g##k##a.x); if (lane == 63 && rr != 0.0f) atomicAdd(&sS[10 + 0 * 21 + k], rr); \
    rr = dppsum64(g##k##a.y); if (lane == 63 && rr != 0.0f) atomicAdd(&sS[10 + 1 * 21 + k], rr); \
    rr = dppsum64(g##k##b.x); if (lane == 63 && rr != 0.0f) atomicAdd(&sS[10 + 2 * 21 + k], rr); \
    rr = dppsum64(g##k##b.y); if (lane == 63 && rr != 0.0f) atomicAdd(&sS[10 + 3 * 21 + k], rr); }
    GF(0) GF(1) GF(2) GF(3) GF(4) GF(5) GF(6)
#undef GF
#pragma unroll
    for (int j = 0; j < 14; j++) {
      if (j < FS) {
        float m = (float)((pat >> j) & 1u);   // sentinel lanes contribute 0 (aQ==0)
        rr = dppsum64(m * aQa.x); if (lane == 63 && rr != 0.0f) atomicAdd(&sS[10 + 0 * 21 + FBE + j], rr);
        rr = dppsum64(m * aQa.y); if (lane == 63 && rr != 0.0f) atomicAdd(&sS[10 + 1 * 21 + FBE + j], rr);
        rr = dppsum64(m * aQb.x); if (lane == 63 && rr != 0.0f) atomicAdd(&sS[10 + 2 * 21 + FBE + j], rr);
        rr = dppsum64(m * aQb.y); if (lane == 63 && rr != 0.0f) atomicAdd(&sS[10 + 3 * 21 + FBE + j], rr);
      }
    }
  }
  __syncthreads();
  if (tx < SUMS_STRIDE) {
    float v = sS[tx];
    if (v != 0.0f) gatomic(&ws[OFF_SUMS + t * SUMS_STRIDE + tx], v);
  }
}

__global__ __launch_bounds__(BT) void kc(
    const float* p0,
    const float* W1_2, const float* b1_2, const float* W2_2, const float* b2_2,
    const float* W1_3, const float* b1_3, const float* W2_3, const float* b2_3,
    float* ws) {
  __shared__ float4 tabEX[128], tabS0[128], tabS1[128];
  __shared__ float sS[SUMS_STRIDE];
  int b = blockIdx.x;
  int t, sub;
  if (b < NSTEP2 * KC_B2) { t = b / KC_B2; sub = b % KC_B2; }
  else { int b3 = b - NSTEP2 * KC_B2; t = NSTEP2 + b3 / KC_B3; sub = b3 % KC_B3; }
  int rep = ((const int*)ws)[OFF_REP + t];
  if (rep != t) return;   // only representative steps enumerate
  float pval = (t == 0) ? p0[0] : 0.0f;
  if (t < NSTEP2) kc_work<21>(t, sub, pval, W1_2, b1_2, W2_2, b2_2, ws, tabEX, tabS0, tabS1, sS);
  else            kc_work<20>(t, sub, pval, W1_3, b1_3, W2_3, b2_3, ws, tabEX, tabS0, tabS1, sS);
}

// =================== Kernel D: p-chain + finalize gradient outputs ===================
__global__ __launch_bounds__(256) void kd(const float* p0in,
                   const float* W1_2, const float* b1_2, const float* W2_2, const float* b2_2,
                   const float* W1_3, const float* b1_3, const float* W2_3, const float* b2_3,
                   const float* ws, float* out) {
  __shared__ float sS[NSTEPS * SUMS_STRIDE];   // 12 KB
  __shared__ float sKEYB[128];
  __shared__ float sk_s[NSTEPS][4], hk_s[NSTEPS][4], pp_s[NSTEPS], s0i_s[NSTEPS];
  __shared__ int sREP[NSTEPS];
  int tx = threadIdx.x;
  for (int i = tx; i < NSTEPS * SUMS_STRIDE; i += 256) sS[i] = ws[OFF_SUMS + i];
  for (int i = tx; i < 128; i += 256) sKEYB[i] = ws[OFF_KEYB + i];
  if (tx < NSTEPS) sREP[tx] = ((const int*)ws)[OFF_REP + tx];
  __syncthreads();
  if (tx == 0) {
    float p = p0in[0];
    out[0] = p;
    for (int t = 0; t < NSTEPS; t++) {
      int g = (t < NSTEP2) ? 0 : 1;
      int L = g ? L3 : L2;
      const float* W1 = g ? W1_3 : W1_2;
      const float* W2 = g ? W2_3 : W2_2;
      float b2s = (g ? b2_3 : b2_2)[0];
      pp_s[t] = p;
      float outk = b2s;
      for (int h = 0; h < 4; h++)
        outk += W2[h] * fast_tanh(sKEYB[t * 4 + h] + p * W1[h * (L + 1)]);
      float Se = sS[sREP[t] * SUMS_STRIDE + 0];
      p = fast_exp(outk) / Se;
      out[1 + t] = p;
    }
  }
  __syncthreads();
  if (tx < NSTEPS) {
    int t = tx; int g = (t < NSTEP2) ? 0 : 1; int L = g ? L3 : L2;
    const float* W1 = g ? W1_3 : W1_2;
    const float* W2 = g ? W2_3 : W2_2;
    float p = pp_s[t];
    s0i_s[t] = 1.0f / sS[sREP[t] * SUMS_STRIDE + 0];
    for (int h = 0; h < 4; h++) {
      float hk = fast_tanh(sKEYB[t * 4 + h] + p * W1[h * (L + 1)]);
      hk_s[t][h] = hk;
      sk_s[t][h] = (1.0f - hk * hk) * W2[h];
    }
  }
  __syncthreads();
  const unsigned* cbp = (const unsigned*)ws;
  for (int o = 33 + tx; o < 223; o += blockDim.x) {
    float val = 0.0f;
    if (o < 130) {
      if (o < 121) {
        int e = o - 33; int h = e / 22, d = e % 22;
        for (int t = 0; t < NSTEP2; t++) {
          int rp = sREP[t];
          float xk = (d == 0) ? pp_s[t] : (float)((cbp[OFF_CB + t] >> (d - 1)) & 1);
          float gs = (d == 0) ? pp_s[t] * sS[rp * SUMS_STRIDE + 2 + h]
                              : sS[rp * SUMS_STRIDE + 10 + h * 21 + (d - 1)];
          val += sk_s[t][h] * xk - gs * s0i_s[t];
        }
      } else if (o < 125) { int h = o - 121;
        for (int t = 0; t < NSTEP2; t++) val += sk_s[t][h] - sS[sREP[t] * SUMS_STRIDE + 2 + h] * s0i_s[t];
      } else if (o < 129) { int h = o - 125;
        for (int t = 0; t < NSTEP2; t++) val += hk_s[t][h] - sS[sREP[t] * SUMS_STRIDE + 6 + h] * s0i_s[t];
      } else {
        for (int t = 0; t < NSTEP2; t++) val += 1.0f - sS[sREP[t] * SUMS_STRIDE + 1] * s0i_s[t];
      }
    } else {
      if (o < 214) {
        int e = o - 130; int h = e / 21, d = e % 21;
        for (int t = NSTEP2; t < NSTEPS; t++) {
          int rp = sREP[t];
          float xk = (d == 0) ? pp_s[t] : (float)((cbp[OFF_CB + t] >> (d - 1)) & 1);
          float gs = (d == 0) ? pp_s[t] * sS[rp * SUMS_STRIDE + 2 + h]
                              : sS[rp * SUMS_STRIDE + 10 + h * 21 + (d - 1)];
          val += sk_s[t][h] * xk - gs * s0i_s[t];
        }
      } else if (o < 218) { int h = o - 214;
        for (int t = NSTEP2; t < NSTEPS; t++) val += sk_s[t][h] - sS[sREP[t] * SUMS_STRIDE + 2 + h] * s0i_s[t];
      } else if (o < 222) { int h = o - 218;
        for (int t = NSTEP2; t < NSTEPS; t++) val += hk_s[t][h] - sS[sREP[t] * SUMS_STRIDE + 6 + h] * s0i_s[t];
      } else {
        for (int t = NSTEP2; t < NSTEPS; t++) val += 1.0f - sS[sREP[t] * SUMS_STRIDE + 1] * s0i_s[t];
      }
    }
    out[o] = val;
  }
}

extern "C" void kernel_launch(void* const* d_in, const int* in_sizes, int n_in,
                              void* d_out, int out_size, void* d_ws, size_t ws_size,
                              hipStream_t stream) {
  const float* p0   = (const float*)d_in[0];
  const float* sel  = (const float*)d_in[1];
  const float* W1_2 = (const float*)d_in[2]; const float* b1_2 = (const float*)d_in[3];
  const float* W2_2 = (const float*)d_in[4]; const float* b2_2 = (const float*)d_in[5];
  const float* W1_3 = (const float*)d_in[6]; const float* b1_3 = (const float*)d_in[7];
  const float* W2_3 = (const float*)d_in[8]; const float* b2_3 = (const float*)d_in[9];
  float* out = (float*)d_out;
  float* ws  = (float*)d_ws;
  hipLaunchKernelGGL(kz, dim3(1 + (NPAT2P + NPAT3P + 255) / 256), dim3(256), 0, stream,
                     p0, sel, W1_2, b1_2, W1_3, b1_3, ws);
  hipLaunchKernelGGL(kc, dim3(KC_BLOCKS), dim3(BT), 0, stream, p0,
                     W1_2, b1_2, W2_2, b2_2, W1_3, b1_3, W2_3, b2_3, ws);
  hipLaunchKernelGGL(kd, dim3(1), dim3(256), 0, stream, p0,
                     W1_2, b1_2, W2_2, b2_2, W1_3, b1_3, W2_3, b2_3, ws, out);
}